// Round 6
// baseline (121.332 us; speedup 1.0000x reference)
//
#include <hip/hip_runtime.h>

#define B_   8
#define N_   307
#define BN   (B_ * N_)          // 2456 blocks
#define OUT_ELEMS (BN * 64 * 64)

typedef float f32x4 __attribute__((ext_vector_type(4)));
typedef short s16x8 __attribute__((ext_vector_type(8)));

__device__ __forceinline__ unsigned short f2bf(float x) {
    unsigned int u = __builtin_bit_cast(unsigned int, x);
    u += 0x7FFFu + ((u >> 16) & 1u);        // round-to-nearest-even
    return (unsigned short)(u >> 16);
}

// XOR-swizzle on 16B frag rows (G4 / m201): bijective within 8-row groups.
__device__ __forceinline__ int swz(int row) { return row ^ ((row >> 3) & 7); }

__device__ __forceinline__ s16x8 ldfrag(const unsigned short* p) {
    return *reinterpret_cast<const s16x8*>(p);
}

__device__ __forceinline__ s16x8 cvt8(float4 lo, float4 hi) {
    s16x8 f;
    f[0] = (short)f2bf(lo.x); f[1] = (short)f2bf(lo.y);
    f[2] = (short)f2bf(lo.z); f[3] = (short)f2bf(lo.w);
    f[4] = (short)f2bf(hi.x); f[5] = (short)f2bf(hi.y);
    f[6] = (short)f2bf(hi.z); f[7] = (short)f2bf(hi.w);
    return f;
}

// 64x64 row-major fp32 (K x N) global -> bf16 B-operand frag layout (swizzled)
__device__ __forceinline__ void stage_B(const float* __restrict__ src,
                                        unsigned short* dst, int tid) {
    const float4* s4 = reinterpret_cast<const float4*>(src);
#pragma unroll
    for (int i = 0; i < 4; ++i) {
        int idx = i * 256 + tid;
        float4 v = s4[idx];
        int k  = idx >> 4;
        int n0 = (idx & 15) << 2;
        int ki = k >> 5;
        int qd = (k >> 3) & 3;
        int j  = k & 7;
        float vv[4] = {v.x, v.y, v.z, v.w};
#pragma unroll
        for (int c = 0; c < 4; ++c) {
            int n = n0 + c;
            int row = ((n >> 4) * 2 + ki) * 64 + (qd << 4) + (n & 15);
            dst[(swz(row) << 3) + j] = f2bf(vv[c]);
        }
    }
}

__global__ __launch_bounds__(256, 4) void mta_kernel(
    const float* __restrict__ Xq, const float* __restrict__ Xk,
    const float* __restrict__ Xv, const float* __restrict__ maskp,
    const float* __restrict__ res, const float* __restrict__ Wq,
    const float* __restrict__ Wk, const float* __restrict__ Wv,
    const float* __restrict__ Wfc, const float* __restrict__ lnS,
    const float* __restrict__ lnB, float* __restrict__ out,
    float* __restrict__ scores_out)
{
    // 32KB LDS. Attention: wave w == head w -> ZERO barriers from projection
    // end to fc (softmax fully in-wave; attn->PV transpose via per-wave
    // private LDS scratch = this wave's dead sKf/sQf quarters; same-wave
    // ds ordering needs no barrier). res folded into MFMA C-operand,
    // double-banked so next column-tile's res loads hide under compute.
    __shared__ __align__(16) unsigned char smem[32768];
    unsigned short* sKf = (unsigned short*)(smem);           // 8KB scores B-frags (K) / attn scratch
    unsigned short* sQf = (unsigned short*)(smem + 8192);    // 8KB scores A-frags (Q) / attn scratch / ctx frags
    unsigned short* sVf = (unsigned short*)(smem + 16384);   // 8KB PV B-frags (V)
    unsigned short* sWA = (unsigned short*)(smem + 24576);   // 8KB W frags (proj) / Wfc frags (fc)

    const int bn   = blockIdx.x;
    const int tid  = threadIdx.x;
    const int w    = tid >> 6;
    const int lane = tid & 63;
    const int quad = lane >> 4;
    const int l16  = lane & 15;
    const size_t base64 = (size_t)bn * 4096;

    // ---------------- Projections: Q (scaled 1/4), K, V ----------------
#pragma unroll 1
    for (int pj = 0; pj < 3; ++pj) {
        const float* Xs = (pj == 0) ? Xq : (pj == 1) ? Xk : Xv;
        const float* Ws = (pj == 0) ? Wq : (pj == 1) ? Wk : Wv;
        // A-frags direct from global: lane holds X[m=w*16+l16][k=quad*8+ki*32 ..+7]
        const float* p = Xs + base64 + (w * 16 + l16) * 64 + quad * 8;
        float4 x0 = *(const float4*)(p);      float4 x1 = *(const float4*)(p + 4);
        float4 x2 = *(const float4*)(p + 32); float4 x3 = *(const float4*)(p + 36);
        stage_B(Ws, sWA, tid);
        __syncthreads();
        s16x8 a0 = cvt8(x0, x1);
        s16x8 a1 = cvt8(x2, x3);
#pragma unroll
        for (int nt = 0; nt < 4; ++nt) {
            f32x4 acc = {0.f, 0.f, 0.f, 0.f};
            s16x8 b0 = ldfrag(sWA + (swz((nt * 2 + 0) * 64 + lane) << 3));
            s16x8 b1 = ldfrag(sWA + (swz((nt * 2 + 1) * 64 + lane) << 3));
            acc = __builtin_amdgcn_mfma_f32_16x16x32_bf16(a0, b0, acc, 0, 0, 0);
            acc = __builtin_amdgcn_mfma_f32_16x16x32_bf16(a1, b1, acc, 0, 0, 0);
            if (pj == 0) {          // Q -> scores A-frag layout, fold 1/sqrt(16)
#pragma unroll
                for (int r = 0; r < 4; ++r) {
                    int rowq = (nt * 4 + w) * 32 + ((l16 >> 3) << 4) + quad * 4 + r;
                    sQf[(swz(rowq) << 3) + (l16 & 7)] = f2bf(acc[r] * 0.25f);
                }
            } else if (pj == 1) {   // K -> scores B-frag layout
#pragma unroll
                for (int r = 0; r < 4; ++r) {
                    int rowk = (nt * 4 + w) * 32 + ((l16 >> 3) << 4) + quad * 4 + r;
                    sKf[(swz(rowk) << 3) + (l16 & 7)] = f2bf(acc[r]);
                }
            } else {                // V -> PV B-frag layout (nt == head)
#pragma unroll
                for (int r = 0; r < 4; ++r) {
                    int kk = w * 16 + quad * 4 + r;
                    int rowv = (nt * 2 + (kk >> 5)) * 64 + (((kk >> 3) & 3) << 4) + l16;
                    sVf[(swz(rowv) << 3) + (kk & 7)] = f2bf(acc[r]);
                }
            }
        }
        __syncthreads();
    }

    // Wfc -> sWA now (region dead until fc; latency hides under attention)
    stage_B(Wfc, sWA, tid);

    // ---------------- Attention: wave w handles head h = w, barrier-free ----------------
    const int h = w;
    const size_t sbase = ((size_t)(bn * 4 + h)) << 12;

    // mask bits for the 16 q-rows this thread touches (q = mt*16+quad*4+r)
    unsigned mbits = 0u;
#pragma unroll
    for (int mt = 0; mt < 4; ++mt) {
        float4 mv = *reinterpret_cast<const float4*>(maskp + bn * 64 + mt * 16 + quad * 4);
        mbits |= (mv.x > 0.5f ? 1u : 0u) << (mt * 4 + 0);
        mbits |= (mv.y > 0.5f ? 1u : 0u) << (mt * 4 + 1);
        mbits |= (mv.z > 0.5f ? 1u : 0u) << (mt * 4 + 2);
        mbits |= (mv.w > 0.5f ? 1u : 0u) << (mt * 4 + 3);
    }

    // Q/K frags for this head -> regs (then our sKf/sQf quarters are dead)
    const s16x8 zf = {0, 0, 0, 0, 0, 0, 0, 0};
    s16x8 aq[4], bk[4];
#pragma unroll
    for (int t = 0; t < 4; ++t) {
        aq[t] = (lane < 32) ? ldfrag(sQf + (swz((h * 4 + t) * 32 + lane) << 3)) : zf;
        bk[t] = (lane < 32) ? ldfrag(sKf + (swz((h * 4 + t) * 32 + lane) << 3)) : zf;
    }
    // per-wave private scratch (own 2KB quarters, 4KB total = one 32-col half)
    unsigned short* scrA = sKf + w * 1024;   // u16 units (2KB)
    unsigned short* scrB = sQf + w * 1024;   // u16 units (2KB)

    const float* rp = res + sbase + quad * 256 + l16;         // + mt*1024 + r*64 + nt*16
    float*       sp = scores_out + sbase + quad * 256 + l16;  // same offsets

    f32x4 ctx[4];
#pragma unroll
    for (int mt = 0; mt < 4; ++mt) ctx[mt] = {0.f, 0.f, 0.f, 0.f};

    f32x4 acc[2][4];
#pragma unroll
    for (int mt = 0; mt < 4; ++mt)
#pragma unroll
        for (int r = 0; r < 4; ++r)
            acc[0][mt][r] = rp[mt * 1024 + r * 64];           // res for nt=0

#pragma unroll
    for (int nt = 0; nt < 4; ++nt) {
        const int cb = nt & 1, nb = cb ^ 1;
        // scores col-tile nt: S = (Q/4)·K^T + res (res pre-loaded as C-in)
#pragma unroll
        for (int mt = 0; mt < 4; ++mt)
            acc[cb][mt] = __builtin_amdgcn_mfma_f32_16x16x32_bf16(aq[mt], bk[nt], acc[cb][mt], 0, 0, 0);
        if (nt < 3) {   // prefetch next col-tile's res into other bank
#pragma unroll
            for (int mt = 0; mt < 4; ++mt)
#pragma unroll
                for (int r = 0; r < 4; ++r)
                    acc[nb][mt][r] = rp[mt * 1024 + r * 64 + (nt + 1) * 16];
        }
        // mask + store + exp + in-wave column sum (no max-sub: scores bounded,
        // masked -1e9 -> exp underflows to +0)
        float esum = 0.f;
#pragma unroll
        for (int mt = 0; mt < 4; ++mt)
#pragma unroll
            for (int r = 0; r < 4; ++r) {
                float s = acc[cb][mt][r];
                s = ((mbits >> (mt * 4 + r)) & 1u) ? -1e9f : s;
                sp[mt * 1024 + r * 64 + nt * 16] = s;
                float e = __expf(s);
                acc[cb][mt][r] = e;
                esum += e;
            }
        esum += __shfl_xor(esum, 16, 64);
        esum += __shfl_xor(esum, 32, 64);
        float inv = 1.0f / (esum + 1e-30f);
        // attn -> PV A-frag layout in private scratch (k = nt*16+l16)
#pragma unroll
        for (int mt = 0; mt < 4; ++mt) {
            unsigned short* scr = ((mt < 2) ? scrA : scrB) + (mt & 1) * 512;
            int rl = (((nt * 2 + (l16 >> 3)) & 3) << 4) + quad * 4;
#pragma unroll
            for (int r = 0; r < 4; ++r)
                scr[(swz(rl + r) << 3) + (l16 & 7)] = f2bf(acc[cb][mt][r] * inv);
        }
        // after each 32-col half: partial PV (same-wave ds ordering, no barrier)
        if (cb == 1) {
            const int ki = nt >> 1;
            s16x8 bv = ldfrag(sVf + (swz((h * 2 + ki) * 64 + lane) << 3));
#pragma unroll
            for (int mt = 0; mt < 4; ++mt) {
                s16x8 ap = ldfrag(((mt < 2) ? scrA : scrB) + (mt & 1) * 512 + (swz(lane) << 3));
                ctx[mt] = __builtin_amdgcn_mfma_f32_16x16x32_bf16(ap, bv, ctx[mt], 0, 0, 0);
            }
        }
    }

    __syncthreads();   // all waves done with scratch/scores; sQf/sKf free

    // ---------------- fc + residual + layernorm ----------------
    // ctx -> fc A-frag layout: wave h owns columns c = h*16+l16 (rows disjoint per head)
#pragma unroll
    for (int mt = 0; mt < 4; ++mt) {
        int c    = h * 16 + l16;
        int rowb = (mt * 2 + (c >> 5)) * 64 + (((c >> 3) & 3) << 4) + quad * 4;
#pragma unroll
        for (int r = 0; r < 4; ++r)
            sQf[(swz(rowb + r) << 3) + (c & 7)] = f2bf(ctx[mt][r]);
    }
    // residual + LN params (hide under frag writes)
    const int toff = (w * 16 + quad * 4) * 64 + l16;
    float xres[4][4];
    {
        const float* xp = Xq + base64 + toff;
#pragma unroll
        for (int nt = 0; nt < 4; ++nt)
#pragma unroll
            for (int r = 0; r < 4; ++r)
                xres[nt][r] = xp[r * 64 + nt * 16];
    }
    float scl[4], bia[4];
#pragma unroll
    for (int nt = 0; nt < 4; ++nt) {
        scl[nt] = lnS[nt * 16 + l16];
        bia[nt] = lnB[nt * 16 + l16];
    }
    __syncthreads();

    f32x4 oacc[4];
    {
        s16x8 a0 = ldfrag(sQf + (swz((w * 2 + 0) * 64 + lane) << 3));
        s16x8 a1 = ldfrag(sQf + (swz((w * 2 + 1) * 64 + lane) << 3));
#pragma unroll
        for (int nt = 0; nt < 4; ++nt) {
            f32x4 a = {0.f, 0.f, 0.f, 0.f};
            s16x8 b0 = ldfrag(sWA + (swz((nt * 2 + 0) * 64 + lane) << 3));
            s16x8 b1 = ldfrag(sWA + (swz((nt * 2 + 1) * 64 + lane) << 3));
            a = __builtin_amdgcn_mfma_f32_16x16x32_bf16(a0, b0, a, 0, 0, 0);
            a = __builtin_amdgcn_mfma_f32_16x16x32_bf16(a1, b1, a, 0, 0, 0);
            oacc[nt] = a;
        }
    }

#pragma unroll
    for (int r = 0; r < 4; ++r) {
        float px[4], sum = 0.f, sq = 0.f;
#pragma unroll
        for (int nt = 0; nt < 4; ++nt) {
            float x = oacc[nt][r] + xres[nt][r];
            px[nt] = x; sum += x; sq += x * x;
        }
#pragma unroll
        for (int m = 1; m <= 8; m <<= 1) {
            sum += __shfl_xor(sum, m, 64);
            sq  += __shfl_xor(sq,  m, 64);
        }
        float mu   = sum * 0.015625f;
        float var  = sq * 0.015625f - mu * mu;
        float rstd = rsqrtf(var + 1e-5f);
#pragma unroll
        for (int nt = 0; nt < 4; ++nt) {
            out[base64 + toff + r * 64 + nt * 16] = (px[nt] - mu) * rstd * scl[nt] + bia[nt];
        }
    }
}

extern "C" void kernel_launch(void* const* d_in, const int* in_sizes, int n_in,
                              void* d_out, int out_size, void* d_ws, size_t ws_size,
                              hipStream_t stream) {
    const float* Xq   = (const float*)d_in[0];
    const float* Xk   = (const float*)d_in[1];
    const float* Xv   = (const float*)d_in[2];
    const float* msk  = (const float*)d_in[3];
    const float* res  = (const float*)d_in[4];
    const float* Wq   = (const float*)d_in[5];
    const float* Wk   = (const float*)d_in[6];
    const float* Wv   = (const float*)d_in[7];
    const float* Wfc  = (const float*)d_in[8];
    const float* lnS  = (const float*)d_in[9];
    const float* lnB  = (const float*)d_in[10];
    float* out    = (float*)d_out;
    float* scores = out + OUT_ELEMS;
    mta_kernel<<<BN, 256, 0, stream>>>(Xq, Xk, Xv, msk, res, Wq, Wk, Wv, Wfc,
                                       lnS, lnB, out, scores);
}